// Round 7
// baseline (320.722 us; speedup 1.0000x reference)
//
#include <hip/hip_runtime.h>
#include <hip/hip_bf16.h>
#include <hip/hip_fp16.h>
#include <math.h>

#define N_NODES 50000
#define N_EDGES 600000
#define E_TOT   (N_EDGES + N_NODES)   // 650000 edges incl self-loops
#define F       128
#define HEADS   4
#define DHEAD   32
#define CLS     10
#define CLS_PAD 16

// ---------------- CSR build (self-loops placed deterministically, no atomics for them) ----------------

__global__ void count_deg(const int* __restrict__ ei, int* __restrict__ deg) {
    int e = blockIdx.x * blockDim.x + threadIdx.x;
    if (e >= N_EDGES) return;
    atomicAdd(&deg[ei[N_EDGES + e]], 1);
}

#define SCAN_BLOCK 256
#define SCAN_ITEMS 4   // chunk = 1024

__global__ void scan1(const int* __restrict__ deg, int* __restrict__ ptr,
                      int* __restrict__ blockSums, int n) {
    __shared__ int sdata[SCAN_BLOCK];
    int t = threadIdx.x;
    int base = blockIdx.x * (SCAN_BLOCK * SCAN_ITEMS) + t * SCAN_ITEMS;
    int v[SCAN_ITEMS];
    int sum = 0;
    #pragma unroll
    for (int i = 0; i < SCAN_ITEMS; i++) {
        int idx = base + i;
        v[i] = (idx < n) ? (deg[idx] + 1) : 0;   // +1 = self-loop
        sum += v[i];
    }
    sdata[t] = sum;
    __syncthreads();
    for (int off = 1; off < SCAN_BLOCK; off <<= 1) {
        int x = 0;
        if (t >= off) x = sdata[t - off];
        __syncthreads();
        if (t >= off) sdata[t] += x;
        __syncthreads();
    }
    int excl = (t > 0) ? sdata[t - 1] : 0;
    if (t == SCAN_BLOCK - 1) blockSums[blockIdx.x] = sdata[t];
    int run = excl;
    #pragma unroll
    for (int i = 0; i < SCAN_ITEMS; i++) {
        int idx = base + i;
        if (idx < n) ptr[idx] = run;
        run += v[i];
    }
}

// 64-lane shuffle scan (nb <= 64). Replaces the serial 1-thread loop
// (49 dependent global round-trips ~= 12 us of pure latency).
__global__ void scan2(int* __restrict__ blockSums, int nb) {
    int t = threadIdx.x;
    int v = (t < nb) ? blockSums[t] : 0;
    #pragma unroll
    for (int off = 1; off < 64; off <<= 1) {
        int u = __shfl_up(v, off);
        if (t >= off) v += u;
    }
    int excl = __shfl_up(v, 1);
    if (t == 0) excl = 0;
    if (t < nb) blockSums[t] = excl;
}

__global__ void scan3(int* __restrict__ ptr, const int* __restrict__ blockSums,
                      int* __restrict__ cursor, int* __restrict__ csr, int n, int total) {
    int i = blockIdx.x * blockDim.x + threadIdx.x;
    if (i < n) {
        int v = ptr[i] + blockSums[i / (SCAN_BLOCK * SCAN_ITEMS)];
        ptr[i] = v;
        cursor[i] = v + 1;   // real edges start after the self-loop slot
        csr[v] = i;          // self-loop first
    }
    if (i == 0) ptr[n] = total;
}

__global__ void scatter_edges(const int* __restrict__ ei, int* __restrict__ cursor,
                              int* __restrict__ csr_src) {
    int e = blockIdx.x * blockDim.x + threadIdx.x;
    if (e >= N_EDGES) return;
    int s = ei[e], d = ei[N_EDGES + e];
    int pos = atomicAdd(&cursor[d], 1);
    csr_src[pos] = s;
}

// ---------------- W pre-convert: fp32 [k][c] -> fp16 transposed [c][k], XOR-swizzled ----------------

__global__ __launch_bounds__(256) void conv_w(const float* __restrict__ W0,
                                              const float* __restrict__ W1,
                                              __half* __restrict__ Wt0,
                                              __half* __restrict__ Wt1) {
    int idx = blockIdx.x * 256 + threadIdx.x;
    if (idx >= 128 * 128) return;
    int k = idx >> 7, c = idx & 127;
    int e = k ^ ((c & 7) << 3);
    Wt0[c * 128 + e] = __float2half(W0[idx]);
    Wt1[c * 128 + e] = __float2half(W1[idx]);
}

// ---------------- MFMA GEMM + fused attention coefficients ----------------
// SWAPPED operand order: mfma(bf, af) -> lane holds ROW lr, 4 consecutive COLS
// (c2*16 + lg*4 + r). hp store = 8x 8B packed stores; att reduce = 2 shfl rounds.

using half8_t  = __attribute__((ext_vector_type(8))) _Float16;
using floatx4  = __attribute__((ext_vector_type(4))) float;

template<bool HALF_IN>
__global__ __launch_bounds__(256) void gemm_att_mfma(const void* __restrict__ Ain,
                                                     const __half* __restrict__ Wt,
                                                     const float* __restrict__ att_s,
                                                     const float* __restrict__ att_d,
                                                     __half* __restrict__ C,
                                                     float* __restrict__ a_s,
                                                     float* __restrict__ a_d, int nrows) {
    __shared__ _Float16 As[64 * 128];    // 16 KB, swizzled rows
    __shared__ _Float16 Ws[128 * 128];   // 32 KB, pre-swizzled [col][k]
    int t = threadIdx.x;
    int row0 = blockIdx.x * 64;

    // stage Ws: linear 32 KB copy (Wt already transposed+swizzled)
    #pragma unroll
    for (int idx = t; idx < 128 * 128 / 8; idx += 256)
        ((float4*)Ws)[idx] = ((const float4*)Wt)[idx];

    // stage As: 64 rows x 16 groups of 8 elems, swizzled write
    if constexpr (HALF_IN) {
        const __half* A = (const __half*)Ain;
        #pragma unroll
        for (int idx = t; idx < 64 * 16; idx += 256) {
            int r = idx >> 4, g = idx & 15;
            float4 v = make_float4(0.f, 0.f, 0.f, 0.f);
            if (row0 + r < nrows)
                v = *(const float4*)(A + (size_t)(row0 + r) * 128 + g * 8);
            int gs = g ^ (r & 7);
            *(float4*)&As[r * 128 + (gs << 3)] = v;
        }
    } else {
        const float* A = (const float*)Ain;
        #pragma unroll
        for (int idx = t; idx < 64 * 16; idx += 256) {
            int r = idx >> 4, g = idx & 15;
            float4 v0 = make_float4(0.f, 0.f, 0.f, 0.f), v1 = v0;
            if (row0 + r < nrows) {
                const float4* p = (const float4*)(A + (size_t)(row0 + r) * 128 + g * 8);
                v0 = p[0]; v1 = p[1];
            }
            int gs = g ^ (r & 7);
            union { _Float16 h[8]; float4 f; } u;
            u.h[0] = (_Float16)v0.x; u.h[1] = (_Float16)v0.y;
            u.h[2] = (_Float16)v0.z; u.h[3] = (_Float16)v0.w;
            u.h[4] = (_Float16)v1.x; u.h[5] = (_Float16)v1.y;
            u.h[6] = (_Float16)v1.z; u.h[7] = (_Float16)v1.w;
            *(float4*)&As[r * 128 + (gs << 3)] = u.f;
        }
    }
    __syncthreads();

    int wave = t >> 6, l = t & 63;
    int lr = l & 15, lg = l >> 4;        // lr: row lane, lg: k-group / col-quad
    int arow = wave * 16 + lr;

    floatx4 acc[8];
    #pragma unroll
    for (int c2 = 0; c2 < 8; c2++) acc[c2] = (floatx4){0.f, 0.f, 0.f, 0.f};

    #pragma unroll
    for (int ks = 0; ks < 4; ks++) {
        int gk = ks * 4 + lg;            // k-octet index
        half8_t af = *(const half8_t*)&As[arow * 128 + ((gk ^ (arow & 7)) << 3)];
        #pragma unroll
        for (int c2 = 0; c2 < 8; c2++) {
            int col = c2 * 16 + lr;
            half8_t bf = *(const half8_t*)&Ws[col * 128 + ((gk ^ (col & 7)) << 3)];
            // swapped: D^T -> lane holds row=arow, cols c2*16 + lg*4 + {0..3}
            acc[c2] = __builtin_amdgcn_mfma_f32_16x16x32_f16(bf, af, acc[c2], 0, 0, 0);
        }
    }

    int row = row0 + arow;
    bool rowOk = row < nrows;

    // store hp row: 8B packed per c2
    #pragma unroll
    for (int c2 = 0; c2 < 8; c2++) {
        __half2 p0 = __floats2half2_rn(acc[c2][0], acc[c2][1]);
        __half2 p1 = __floats2half2_rn(acc[c2][2], acc[c2][3]);
        uint2 u;
        u.x = *(unsigned*)&p0;
        u.y = *(unsigned*)&p1;
        if (rowOk) ((uint2*)C)[(size_t)row * 32 + c2 * 4 + lg] = u;
    }

    // attention dots: per lane partial over its 32 cols, reduce over lg lanes
    float ps[4] = {0.f, 0.f, 0.f, 0.f}, pd[4] = {0.f, 0.f, 0.f, 0.f};
    #pragma unroll
    for (int c2 = 0; c2 < 8; c2++) {
        #pragma unroll
        for (int r = 0; r < 4; r++) {
            int col = c2 * 16 + lg * 4 + r;
            float v = acc[c2][r];
            ps[c2 >> 1] += v * att_s[col];
            pd[c2 >> 1] += v * att_d[col];
        }
    }
    #pragma unroll
    for (int hh = 0; hh < 4; hh++) {
        ps[hh] += __shfl_xor(ps[hh], 16); ps[hh] += __shfl_xor(ps[hh], 32);
        pd[hh] += __shfl_xor(pd[hh], 16); pd[hh] += __shfl_xor(pd[hh], 32);
    }
    if (lg == 0 && rowOk) {
        *(float4*)(a_s + (size_t)row * 4) = make_float4(ps[0], ps[1], ps[2], ps[3]);
        *(float4*)(a_d + (size_t)row * 4) = make_float4(pd[0], pd[1], pd[2], pd[3]);
    }
}

// ---------------- single-pass aggregate: 2 edges/wave, SCALAR csr, masked single loop ----------
// 2 nodes/block, 32 lanes/edge, uint2 (4 cols) per lane. csr indices stay SCALAR
// (clamped via s_cselect); the only lane-varying select is s = hi ? so : se
// (one v_cndmask of two scalar values) -> gather chain stays 1 VMEM level.
// Halves VMEM instructions, exp count, and VALU per edge vs the 64-lane version.

__global__ __launch_bounds__(128) void gat_aggr(const uint2* __restrict__ hp,
                                                const float* __restrict__ a_s,
                                                const float* __restrict__ a_d,
                                                const int* __restrict__ ptr,
                                                const int* __restrict__ csr,
                                                const float* __restrict__ bias,
                                                const float* __restrict__ gamma,
                                                const float* __restrict__ beta,
                                                uint2* __restrict__ out) {
    int t = threadIdx.x;
    int node = __builtin_amdgcn_readfirstlane(blockIdx.x * 2 + (t >> 6));
    int lane = t & 63;
    int hi = lane >> 5;              // 0: even edge of pair, 1: odd edge
    int lc = lane & 31;              // 4 cols: lc*4 .. +3
    int h = lc >> 3;                 // head
    int beg = ptr[node], end = ptr[node + 1];
    int last = end - 1;
    float adh = a_d[node * 4 + h];
    float a0 = 0.f, a1 = 0.f, a2 = 0.f, a3 = 0.f, l = 0.f;
    for (int i = beg; i < end; i += 8) {
        #pragma unroll
        for (int p = 0; p < 4; p++) {
            int ie = i + 2 * p;                    // scalar
            int io = ie + 1;                       // scalar
            int ie_c = (ie < end) ? ie : last;     // s_cselect
            int io_c = (io < end) ? io : last;     // s_cselect
            int se = csr[ie_c], so = csr[io_c];    // s_load
            int s   = hi ? so : se;                // v_cndmask (scalar srcs)
            int myi = hi ? io : ie;
            float al = a_s[s * 4 + h] + adh;
            al = (al > 0.f) ? al : 0.2f * al;
            float w = (myi < end) ? __expf(al) : 0.f;
            uint2 raw = hp[s * 32 + lc];
            float2 f01 = __half22float2(*(__half2*)&raw.x);
            float2 f23 = __half22float2(*(__half2*)&raw.y);
            l  += w;
            a0 += w * f01.x; a1 += w * f01.y;
            a2 += w * f23.x; a3 += w * f23.y;
        }
    }
    l  += __shfl_xor(l, 32);
    a0 += __shfl_xor(a0, 32); a1 += __shfl_xor(a1, 32);
    a2 += __shfl_xor(a2, 32); a3 += __shfl_xor(a3, 32);
    if (hi == 0) {
        float inv = 1.f / (l + 1e-16f);
        int c = lc * 4;
        const float rs = rsqrtf(1.f + 1e-5f);
        float4 bs = *(const float4*)(bias + c);
        float4 gm = *(const float4*)(gamma + c);
        float4 bt = *(const float4*)(beta + c);
        float v0 = a0 * inv + bs.x; v0 = v0 * (gm.x * rs) + bt.x; v0 = (v0 > 0.f) ? v0 : expm1f(v0);
        float v1 = a1 * inv + bs.y; v1 = v1 * (gm.y * rs) + bt.y; v1 = (v1 > 0.f) ? v1 : expm1f(v1);
        float v2 = a2 * inv + bs.z; v2 = v2 * (gm.z * rs) + bt.z; v2 = (v2 > 0.f) ? v2 : expm1f(v2);
        float v3 = a3 * inv + bs.w; v3 = v3 * (gm.w * rs) + bt.w; v3 = (v3 > 0.f) ? v3 : expm1f(v3);
        __half2 p0 = __floats2half2_rn(v0, v1);
        __half2 p1 = __floats2half2_rn(v2, v3);
        uint2 u;
        u.x = *(unsigned*)&p0;
        u.y = *(unsigned*)&p1;
        out[node * 32 + lc] = u;
    }
}

// ---------------- layer 2: fused [N,128]@[128,10] GEMM + coefficients (A in fp16) ----------------

__global__ __launch_bounds__(256) void cls_fused(const __half* __restrict__ A,
                                                 const float* __restrict__ W2,
                                                 const float* __restrict__ as2,
                                                 const float* __restrict__ ad2,
                                                 float* __restrict__ hp2,
                                                 float* __restrict__ asn,
                                                 float* __restrict__ adn) {
    __shared__ float W2s[128 * CLS];
    __shared__ float av[2 * CLS];
    int t = threadIdx.x;
    for (int idx = t; idx < 128 * CLS; idx += 256) W2s[idx] = W2[idx];
    if (t < CLS) av[t] = as2[t];
    else if (t < 2 * CLS) av[t] = ad2[t - CLS];
    __syncthreads();

    int node = blockIdx.x * 64 + (t >> 2);
    int q = t & 3;
    if (node >= N_NODES) return;
    float acc[CLS];
    #pragma unroll
    for (int c = 0; c < CLS; c++) acc[c] = 0.f;
    const float4* arow = (const float4*)(A + (size_t)node * 128 + q * 32);
    #pragma unroll
    for (int kk = 0; kk < 4; kk++) {
        float4 raw = arow[kk];             // 8 halves
        __half2* hh = (__half2*)&raw;
        #pragma unroll
        for (int j = 0; j < 4; j++) {
            float2 f = __half22float2(hh[j]);
            int k = q * 32 + kk * 8 + j * 2;
            #pragma unroll
            for (int c = 0; c < CLS; c++)
                acc[c] += f.x * W2s[k * CLS + c] + f.y * W2s[(k + 1) * CLS + c];
        }
    }
    #pragma unroll
    for (int c = 0; c < CLS; c++) {
        acc[c] += __shfl_xor(acc[c], 1, 4);
        acc[c] += __shfl_xor(acc[c], 2, 4);
    }
    if (q == 0) {
        float s = 0.f, d = 0.f;
        float* row = hp2 + (size_t)node * CLS_PAD;
        #pragma unroll
        for (int c = 0; c < CLS; c++) {
            row[c] = acc[c];
            s += acc[c] * av[c];
            d += acc[c] * av[CLS + c];
        }
        asn[node] = s;
        adn[node] = d;
    }
}

__global__ __launch_bounds__(256) void gat_aggr2(const float* __restrict__ hp2,
                                                 const float* __restrict__ asn,
                                                 const float* __restrict__ adn,
                                                 const int* __restrict__ ptr,
                                                 const int* __restrict__ csr,
                                                 const float* __restrict__ b2,
                                                 float* __restrict__ out) {
    int gid = blockIdx.x * blockDim.x + threadIdx.x;
    int node = gid >> 4;
    int c = gid & 15;
    if (node >= N_NODES) return;
    int beg = ptr[node], end = ptr[node + 1];
    int last = end - 1;
    int cc = (c < CLS) ? c : 0;
    float adv = adn[node];
    float acc = 0.f, l = 0.f;
    for (int i = beg; i < end; i += 8) {
        int i1 = (i + 1 < end) ? i + 1 : last;
        int i2 = (i + 2 < end) ? i + 2 : last;
        int i3 = (i + 3 < end) ? i + 3 : last;
        int i4 = (i + 4 < end) ? i + 4 : last;
        int i5 = (i + 5 < end) ? i + 5 : last;
        int i6 = (i + 6 < end) ? i + 6 : last;
        int i7 = (i + 7 < end) ? i + 7 : last;
        int s0 = csr[i],  s1 = csr[i1], s2 = csr[i2], s3 = csr[i3];
        int s4 = csr[i4], s5 = csr[i5], s6 = csr[i6], s7 = csr[i7];
        float al0 = asn[s0] + adv;
        float al1 = asn[s1] + adv;
        float al2 = asn[s2] + adv;
        float al3 = asn[s3] + adv;
        float al4 = asn[s4] + adv;
        float al5 = asn[s5] + adv;
        float al6 = asn[s6] + adv;
        float al7 = asn[s7] + adv;
        al0 = (al0 > 0.f) ? al0 : 0.2f * al0;
        al1 = (al1 > 0.f) ? al1 : 0.2f * al1;
        al2 = (al2 > 0.f) ? al2 : 0.2f * al2;
        al3 = (al3 > 0.f) ? al3 : 0.2f * al3;
        al4 = (al4 > 0.f) ? al4 : 0.2f * al4;
        al5 = (al5 > 0.f) ? al5 : 0.2f * al5;
        al6 = (al6 > 0.f) ? al6 : 0.2f * al6;
        al7 = (al7 > 0.f) ? al7 : 0.2f * al7;
        float w0 = __expf(al0);
        float w1 = (i + 1 < end) ? __expf(al1) : 0.f;
        float w2 = (i + 2 < end) ? __expf(al2) : 0.f;
        float w3 = (i + 3 < end) ? __expf(al3) : 0.f;
        float w4 = (i + 4 < end) ? __expf(al4) : 0.f;
        float w5 = (i + 5 < end) ? __expf(al5) : 0.f;
        float w6 = (i + 6 < end) ? __expf(al6) : 0.f;
        float w7 = (i + 7 < end) ? __expf(al7) : 0.f;
        float v0 = hp2[(size_t)s0 * CLS_PAD + cc];
        float v1 = hp2[(size_t)s1 * CLS_PAD + cc];
        float v2 = hp2[(size_t)s2 * CLS_PAD + cc];
        float v3 = hp2[(size_t)s3 * CLS_PAD + cc];
        float v4 = hp2[(size_t)s4 * CLS_PAD + cc];
        float v5 = hp2[(size_t)s5 * CLS_PAD + cc];
        float v6 = hp2[(size_t)s6 * CLS_PAD + cc];
        float v7 = hp2[(size_t)s7 * CLS_PAD + cc];
        l   += w0 + w1 + w2 + w3;
        acc += w0 * v0 + w1 * v1 + w2 * v2 + w3 * v3;
        l   += w4 + w5 + w6 + w7;
        acc += w4 * v4 + w5 * v5 + w6 * v6 + w7 * v7;
    }
    if (c < CLS) out[(size_t)node * CLS + c] = acc / (l + 1e-16f) + b2[c];
}

// ---------------- launch ----------------

extern "C" void kernel_launch(void* const* d_in, const int* in_sizes, int n_in,
                              void* d_out, int out_size, void* d_ws, size_t ws_size,
                              hipStream_t stream) {
    const float* x   = (const float*)d_in[0];
    const int*   ei  = (const int*)  d_in[1];
    const float* W0  = (const float*)d_in[2];
    const float* as0 = (const float*)d_in[3];
    const float* ad0 = (const float*)d_in[4];
    const float* b0  = (const float*)d_in[5];
    const float* g0  = (const float*)d_in[6];
    const float* be0 = (const float*)d_in[7];
    const float* W1  = (const float*)d_in[8];
    const float* as1 = (const float*)d_in[9];
    const float* ad1 = (const float*)d_in[10];
    const float* b1  = (const float*)d_in[11];
    const float* g1  = (const float*)d_in[12];
    const float* be1 = (const float*)d_in[13];
    const float* W2  = (const float*)d_in[14];
    const float* as2 = (const float*)d_in[15];
    const float* ad2 = (const float*)d_in[16];
    const float* b2  = (const float*)d_in[17];

    char* ws = (char*)d_ws;
    size_t off = 0;
    auto alloc = [&](size_t bytes) -> void* {
        void* p = ws + off;
        off += (bytes + 255) & ~(size_t)255;
        return p;
    };
    int*    ptr    = (int*)   alloc((N_NODES + 1) * sizeof(int));
    int*    cursor = (int*)   alloc(N_NODES * sizeof(int));
    int*    bsums  = (int*)   alloc(64 * sizeof(int));
    int*    csr    = (int*)   alloc(E_TOT * sizeof(int));
    __half* hp     = (__half*)alloc((size_t)N_NODES * 128 * sizeof(__half));
    __half* hc     = (__half*)alloc((size_t)N_NODES * 128 * sizeof(__half));
    float*  a_s    = (float*) alloc(N_NODES * 4 * sizeof(float));
    float*  a_d    = (float*) alloc(N_NODES * 4 * sizeof(float));
    float*  hp2    = (float*) alloc((size_t)N_NODES * CLS_PAD * sizeof(float));
    float*  asn    = (float*) alloc(N_NODES * sizeof(float));
    float*  adn    = (float*) alloc(N_NODES * sizeof(float));
    __half* Wt0    = (__half*)alloc(128 * 128 * sizeof(__half));
    __half* Wt1    = (__half*)alloc(128 * 128 * sizeof(__half));

    // ---- CSR build ----
    hipMemsetAsync(cursor, 0, N_NODES * sizeof(int), stream);
    count_deg<<<(N_EDGES + 255) / 256, 256, 0, stream>>>(ei, cursor);
    int nScanBlocks = (N_NODES + SCAN_BLOCK * SCAN_ITEMS - 1) / (SCAN_BLOCK * SCAN_ITEMS);
    scan1<<<nScanBlocks, SCAN_BLOCK, 0, stream>>>(cursor, ptr, bsums, N_NODES);
    scan2<<<1, 64, 0, stream>>>(bsums, nScanBlocks);
    scan3<<<(N_NODES + 255) / 256, 256, 0, stream>>>(ptr, bsums, cursor, csr, N_NODES, E_TOT);
    scatter_edges<<<(N_EDGES + 255) / 256, 256, 0, stream>>>(ei, cursor, csr);

    // ---- weight pre-convert (independent of CSR) ----
    conv_w<<<64, 256, 0, stream>>>(W0, W1, Wt0, Wt1);

    int gemmBlocks = (N_NODES + 63) / 64;

    // ---- layer 0 ----
    gemm_att_mfma<false><<<gemmBlocks, 256, 0, stream>>>(x, Wt0, as0, ad0, hp, a_s, a_d, N_NODES);
    gat_aggr<<<N_NODES / 2, 128, 0, stream>>>((const uint2*)hp, a_s, a_d, ptr, csr,
                                              b0, g0, be0, (uint2*)hc);

    // ---- layer 1 ----
    gemm_att_mfma<true><<<gemmBlocks, 256, 0, stream>>>(hc, Wt1, as1, ad1, hp, a_s, a_d, N_NODES);
    gat_aggr<<<N_NODES / 2, 128, 0, stream>>>((const uint2*)hp, a_s, a_d, ptr, csr,
                                              b1, g1, be1, (uint2*)hc);

    // ---- layer 2 ----
    cls_fused<<<(N_NODES + 63) / 64, 256, 0, stream>>>(hc, W2, as2, ad2, hp2, asn, adn);
    gat_aggr2<<<(N_NODES * 16 + 255) / 256, 256, 0, stream>>>(hp2, asn, adn, ptr, csr, b2,
                                                              (float*)d_out);
}

// Round 8
// 292.525 us; speedup vs baseline: 1.0964x; 1.0964x over previous
//
#include <hip/hip_runtime.h>
#include <hip/hip_bf16.h>
#include <hip/hip_fp16.h>
#include <math.h>

#define N_NODES 50000
#define N_EDGES 600000
#define E_TOT   (N_EDGES + N_NODES)   // 650000 edges incl self-loops
#define F       128
#define HEADS   4
#define DHEAD   32
#define CLS     10
#define CLS_PAD 16

// ---------------- CSR build (self-loops placed deterministically, no atomics for them) ----------------

__global__ void count_deg(const int* __restrict__ ei, int* __restrict__ deg) {
    int e = blockIdx.x * blockDim.x + threadIdx.x;
    if (e >= N_EDGES) return;
    atomicAdd(&deg[ei[N_EDGES + e]], 1);
}

#define SCAN_BLOCK 256
#define SCAN_ITEMS 4   // chunk = 1024

__global__ void scan1(const int* __restrict__ deg, int* __restrict__ ptr,
                      int* __restrict__ blockSums, int n) {
    __shared__ int sdata[SCAN_BLOCK];
    int t = threadIdx.x;
    int base = blockIdx.x * (SCAN_BLOCK * SCAN_ITEMS) + t * SCAN_ITEMS;
    int v[SCAN_ITEMS];
    int sum = 0;
    #pragma unroll
    for (int i = 0; i < SCAN_ITEMS; i++) {
        int idx = base + i;
        v[i] = (idx < n) ? (deg[idx] + 1) : 0;   // +1 = self-loop
        sum += v[i];
    }
    sdata[t] = sum;
    __syncthreads();
    for (int off = 1; off < SCAN_BLOCK; off <<= 1) {
        int x = 0;
        if (t >= off) x = sdata[t - off];
        __syncthreads();
        if (t >= off) sdata[t] += x;
        __syncthreads();
    }
    int excl = (t > 0) ? sdata[t - 1] : 0;
    if (t == SCAN_BLOCK - 1) blockSums[blockIdx.x] = sdata[t];
    int run = excl;
    #pragma unroll
    for (int i = 0; i < SCAN_ITEMS; i++) {
        int idx = base + i;
        if (idx < n) ptr[idx] = run;
        run += v[i];
    }
}

// 64-lane shuffle scan (nb <= 64). Replaces the serial 1-thread loop
// (49 dependent global round-trips ~= 10 us of pure latency). Verified correct in R7.
__global__ void scan2(int* __restrict__ blockSums, int nb) {
    int t = threadIdx.x;
    int v = (t < nb) ? blockSums[t] : 0;
    #pragma unroll
    for (int off = 1; off < 64; off <<= 1) {
        int u = __shfl_up(v, off);
        if (t >= off) v += u;
    }
    int excl = __shfl_up(v, 1);
    if (t == 0) excl = 0;
    if (t < nb) blockSums[t] = excl;
}

__global__ void scan3(int* __restrict__ ptr, const int* __restrict__ blockSums,
                      int* __restrict__ cursor, int* __restrict__ csr, int n, int total) {
    int i = blockIdx.x * blockDim.x + threadIdx.x;
    if (i < n) {
        int v = ptr[i] + blockSums[i / (SCAN_BLOCK * SCAN_ITEMS)];
        ptr[i] = v;
        cursor[i] = v + 1;   // real edges start after the self-loop slot
        csr[v] = i;          // self-loop first
    }
    if (i == 0) ptr[n] = total;
}

__global__ void scatter_edges(const int* __restrict__ ei, int* __restrict__ cursor,
                              int* __restrict__ csr_src) {
    int e = blockIdx.x * blockDim.x + threadIdx.x;
    if (e >= N_EDGES) return;
    int s = ei[e], d = ei[N_EDGES + e];
    int pos = atomicAdd(&cursor[d], 1);
    csr_src[pos] = s;
}

// ---------------- W pre-convert: fp32 [k][c] -> fp16 transposed [c][k], XOR-swizzled ----------------

__global__ __launch_bounds__(256) void conv_w(const float* __restrict__ W0,
                                              const float* __restrict__ W1,
                                              __half* __restrict__ Wt0,
                                              __half* __restrict__ Wt1) {
    int idx = blockIdx.x * 256 + threadIdx.x;
    if (idx >= 128 * 128) return;
    int k = idx >> 7, c = idx & 127;
    int e = k ^ ((c & 7) << 3);
    Wt0[c * 128 + e] = __float2half(W0[idx]);
    Wt1[c * 128 + e] = __float2half(W1[idx]);
}

// ---------------- MFMA GEMM + fused attention coefficients ----------------
// SWAPPED operand order: mfma(bf, af) -> lane holds ROW lr, 4 consecutive COLS
// (c2*16 + lg*4 + r). hp store = 8x 8B packed stores; att reduce = 2 shfl rounds.

using half8_t  = __attribute__((ext_vector_type(8))) _Float16;
using floatx4  = __attribute__((ext_vector_type(4))) float;

template<bool HALF_IN>
__global__ __launch_bounds__(256) void gemm_att_mfma(const void* __restrict__ Ain,
                                                     const __half* __restrict__ Wt,
                                                     const float* __restrict__ att_s,
                                                     const float* __restrict__ att_d,
                                                     __half* __restrict__ C,
                                                     float* __restrict__ a_s,
                                                     float* __restrict__ a_d, int nrows) {
    __shared__ _Float16 As[64 * 128];    // 16 KB, swizzled rows
    __shared__ _Float16 Ws[128 * 128];   // 32 KB, pre-swizzled [col][k]
    int t = threadIdx.x;
    int row0 = blockIdx.x * 64;

    // stage Ws: linear 32 KB copy (Wt already transposed+swizzled)
    #pragma unroll
    for (int idx = t; idx < 128 * 128 / 8; idx += 256)
        ((float4*)Ws)[idx] = ((const float4*)Wt)[idx];

    // stage As: 64 rows x 16 groups of 8 elems, swizzled write
    if constexpr (HALF_IN) {
        const __half* A = (const __half*)Ain;
        #pragma unroll
        for (int idx = t; idx < 64 * 16; idx += 256) {
            int r = idx >> 4, g = idx & 15;
            float4 v = make_float4(0.f, 0.f, 0.f, 0.f);
            if (row0 + r < nrows)
                v = *(const float4*)(A + (size_t)(row0 + r) * 128 + g * 8);
            int gs = g ^ (r & 7);
            *(float4*)&As[r * 128 + (gs << 3)] = v;
        }
    } else {
        const float* A = (const float*)Ain;
        #pragma unroll
        for (int idx = t; idx < 64 * 16; idx += 256) {
            int r = idx >> 4, g = idx & 15;
            float4 v0 = make_float4(0.f, 0.f, 0.f, 0.f), v1 = v0;
            if (row0 + r < nrows) {
                const float4* p = (const float4*)(A + (size_t)(row0 + r) * 128 + g * 8);
                v0 = p[0]; v1 = p[1];
            }
            int gs = g ^ (r & 7);
            union { _Float16 h[8]; float4 f; } u;
            u.h[0] = (_Float16)v0.x; u.h[1] = (_Float16)v0.y;
            u.h[2] = (_Float16)v0.z; u.h[3] = (_Float16)v0.w;
            u.h[4] = (_Float16)v1.x; u.h[5] = (_Float16)v1.y;
            u.h[6] = (_Float16)v1.z; u.h[7] = (_Float16)v1.w;
            *(float4*)&As[r * 128 + (gs << 3)] = u.f;
        }
    }
    __syncthreads();

    int wave = t >> 6, l = t & 63;
    int lr = l & 15, lg = l >> 4;        // lr: row lane, lg: k-group / col-quad
    int arow = wave * 16 + lr;

    floatx4 acc[8];
    #pragma unroll
    for (int c2 = 0; c2 < 8; c2++) acc[c2] = (floatx4){0.f, 0.f, 0.f, 0.f};

    #pragma unroll
    for (int ks = 0; ks < 4; ks++) {
        int gk = ks * 4 + lg;            // k-octet index
        half8_t af = *(const half8_t*)&As[arow * 128 + ((gk ^ (arow & 7)) << 3)];
        #pragma unroll
        for (int c2 = 0; c2 < 8; c2++) {
            int col = c2 * 16 + lr;
            half8_t bf = *(const half8_t*)&Ws[col * 128 + ((gk ^ (col & 7)) << 3)];
            // swapped: D^T -> lane holds row=arow, cols c2*16 + lg*4 + {0..3}
            acc[c2] = __builtin_amdgcn_mfma_f32_16x16x32_f16(bf, af, acc[c2], 0, 0, 0);
        }
    }

    int row = row0 + arow;
    bool rowOk = row < nrows;

    // store hp row: 8B packed per c2
    #pragma unroll
    for (int c2 = 0; c2 < 8; c2++) {
        __half2 p0 = __floats2half2_rn(acc[c2][0], acc[c2][1]);
        __half2 p1 = __floats2half2_rn(acc[c2][2], acc[c2][3]);
        uint2 u;
        u.x = *(unsigned*)&p0;
        u.y = *(unsigned*)&p1;
        if (rowOk) ((uint2*)C)[(size_t)row * 32 + c2 * 4 + lg] = u;
    }

    // attention dots: per lane partial over its 32 cols, reduce over lg lanes
    float ps[4] = {0.f, 0.f, 0.f, 0.f}, pd[4] = {0.f, 0.f, 0.f, 0.f};
    #pragma unroll
    for (int c2 = 0; c2 < 8; c2++) {
        #pragma unroll
        for (int r = 0; r < 4; r++) {
            int col = c2 * 16 + lg * 4 + r;
            float v = acc[c2][r];
            ps[c2 >> 1] += v * att_s[col];
            pd[c2 >> 1] += v * att_d[col];
        }
    }
    #pragma unroll
    for (int hh = 0; hh < 4; hh++) {
        ps[hh] += __shfl_xor(ps[hh], 16); ps[hh] += __shfl_xor(ps[hh], 32);
        pd[hh] += __shfl_xor(pd[hh], 16); pd[hh] += __shfl_xor(pd[hh], 32);
    }
    if (lg == 0 && rowOk) {
        *(float4*)(a_s + (size_t)row * 4) = make_float4(ps[0], ps[1], ps[2], ps[3]);
        *(float4*)(a_d + (size_t)row * 4) = make_float4(pd[0], pd[1], pd[2], pd[3]);
    }
}

// ---------------- single-pass aggregate (R5-proven: unroll-8 -> unroll-4 -> tail) ----------
// 2 nodes/block, 64 threads/node, half2 per lane (2 cols). exp fused inline.
// node wave-uniform via readfirstlane -> ptr/csr loads stay scalar (s_load).

__global__ __launch_bounds__(128) void gat_aggr(const __half2* __restrict__ hp,
                                                const float* __restrict__ a_s,
                                                const float* __restrict__ a_d,
                                                const int* __restrict__ ptr,
                                                const int* __restrict__ csr,
                                                const float* __restrict__ bias,
                                                const float* __restrict__ gamma,
                                                const float* __restrict__ beta,
                                                __half2* __restrict__ out) {
    int t = threadIdx.x;
    int node = __builtin_amdgcn_readfirstlane(blockIdx.x * 2 + (t >> 6));
    int local = t & 63;
    int h = local >> 4;
    int beg = ptr[node], end = ptr[node + 1];
    float adh = a_d[(size_t)node * 4 + h];
    float ax = 0.f, ay = 0.f, l = 0.f;
    int i = beg;
    for (; i + 7 < end; i += 8) {
        int s0 = csr[i],     s1 = csr[i + 1], s2 = csr[i + 2], s3 = csr[i + 3];
        int s4 = csr[i + 4], s5 = csr[i + 5], s6 = csr[i + 6], s7 = csr[i + 7];
        float al0 = a_s[(size_t)s0 * 4 + h] + adh;
        float al1 = a_s[(size_t)s1 * 4 + h] + adh;
        float al2 = a_s[(size_t)s2 * 4 + h] + adh;
        float al3 = a_s[(size_t)s3 * 4 + h] + adh;
        float al4 = a_s[(size_t)s4 * 4 + h] + adh;
        float al5 = a_s[(size_t)s5 * 4 + h] + adh;
        float al6 = a_s[(size_t)s6 * 4 + h] + adh;
        float al7 = a_s[(size_t)s7 * 4 + h] + adh;
        al0 = (al0 > 0.f) ? al0 : 0.2f * al0;
        al1 = (al1 > 0.f) ? al1 : 0.2f * al1;
        al2 = (al2 > 0.f) ? al2 : 0.2f * al2;
        al3 = (al3 > 0.f) ? al3 : 0.2f * al3;
        al4 = (al4 > 0.f) ? al4 : 0.2f * al4;
        al5 = (al5 > 0.f) ? al5 : 0.2f * al5;
        al6 = (al6 > 0.f) ? al6 : 0.2f * al6;
        al7 = (al7 > 0.f) ? al7 : 0.2f * al7;
        float w0 = __expf(al0), w1 = __expf(al1), w2 = __expf(al2), w3 = __expf(al3);
        float w4 = __expf(al4), w5 = __expf(al5), w6 = __expf(al6), w7 = __expf(al7);
        float2 v0 = __half22float2(hp[(size_t)s0 * 64 + local]);
        float2 v1 = __half22float2(hp[(size_t)s1 * 64 + local]);
        float2 v2 = __half22float2(hp[(size_t)s2 * 64 + local]);
        float2 v3 = __half22float2(hp[(size_t)s3 * 64 + local]);
        float2 v4 = __half22float2(hp[(size_t)s4 * 64 + local]);
        float2 v5 = __half22float2(hp[(size_t)s5 * 64 + local]);
        float2 v6 = __half22float2(hp[(size_t)s6 * 64 + local]);
        float2 v7 = __half22float2(hp[(size_t)s7 * 64 + local]);
        l  += w0 + w1 + w2 + w3;
        ax += w0 * v0.x + w1 * v1.x + w2 * v2.x + w3 * v3.x;
        ay += w0 * v0.y + w1 * v1.y + w2 * v2.y + w3 * v3.y;
        l  += w4 + w5 + w6 + w7;
        ax += w4 * v4.x + w5 * v5.x + w6 * v6.x + w7 * v7.x;
        ay += w4 * v4.y + w5 * v5.y + w6 * v6.y + w7 * v7.y;
    }
    for (; i + 3 < end; i += 4) {
        int s0 = csr[i], s1 = csr[i + 1], s2 = csr[i + 2], s3 = csr[i + 3];
        float al0 = a_s[(size_t)s0 * 4 + h] + adh;
        float al1 = a_s[(size_t)s1 * 4 + h] + adh;
        float al2 = a_s[(size_t)s2 * 4 + h] + adh;
        float al3 = a_s[(size_t)s3 * 4 + h] + adh;
        al0 = (al0 > 0.f) ? al0 : 0.2f * al0;
        al1 = (al1 > 0.f) ? al1 : 0.2f * al1;
        al2 = (al2 > 0.f) ? al2 : 0.2f * al2;
        al3 = (al3 > 0.f) ? al3 : 0.2f * al3;
        float w0 = __expf(al0), w1 = __expf(al1), w2 = __expf(al2), w3 = __expf(al3);
        float2 v0 = __half22float2(hp[(size_t)s0 * 64 + local]);
        float2 v1 = __half22float2(hp[(size_t)s1 * 64 + local]);
        float2 v2 = __half22float2(hp[(size_t)s2 * 64 + local]);
        float2 v3 = __half22float2(hp[(size_t)s3 * 64 + local]);
        l  += w0 + w1 + w2 + w3;
        ax += w0 * v0.x + w1 * v1.x + w2 * v2.x + w3 * v3.x;
        ay += w0 * v0.y + w1 * v1.y + w2 * v2.y + w3 * v3.y;
    }
    for (; i < end; i++) {
        int s0 = csr[i];
        float al = a_s[(size_t)s0 * 4 + h] + adh;
        al = (al > 0.f) ? al : 0.2f * al;
        float w = __expf(al);
        float2 v = __half22float2(hp[(size_t)s0 * 64 + local]);
        l  += w;
        ax += w * v.x;
        ay += w * v.y;
    }
    float inv = 1.f / (l + 1e-16f);
    int c = local * 2;
    const float rs = rsqrtf(1.f + 1e-5f);
    float2 bs = *(const float2*)(bias + c);
    float2 gm = *(const float2*)(gamma + c);
    float2 bt = *(const float2*)(beta + c);
    float vx = ax * inv + bs.x;
    float vy = ay * inv + bs.y;
    vx = vx * (gm.x * rs) + bt.x;
    vy = vy * (gm.y * rs) + bt.y;
    vx = (vx > 0.f) ? vx : expm1f(vx);
    vy = (vy > 0.f) ? vy : expm1f(vy);
    out[(size_t)node * 64 + local] = __floats2half2_rn(vx, vy);
}

// ---------------- layer 2: fused [N,128]@[128,10] GEMM + coefficients (A in fp16) ----------------

__global__ __launch_bounds__(256) void cls_fused(const __half* __restrict__ A,
                                                 const float* __restrict__ W2,
                                                 const float* __restrict__ as2,
                                                 const float* __restrict__ ad2,
                                                 float* __restrict__ hp2,
                                                 float* __restrict__ asn,
                                                 float* __restrict__ adn) {
    __shared__ float W2s[128 * CLS];
    __shared__ float av[2 * CLS];
    int t = threadIdx.x;
    for (int idx = t; idx < 128 * CLS; idx += 256) W2s[idx] = W2[idx];
    if (t < CLS) av[t] = as2[t];
    else if (t < 2 * CLS) av[t] = ad2[t - CLS];
    __syncthreads();

    int node = blockIdx.x * 64 + (t >> 2);
    int q = t & 3;
    if (node >= N_NODES) return;
    float acc[CLS];
    #pragma unroll
    for (int c = 0; c < CLS; c++) acc[c] = 0.f;
    const float4* arow = (const float4*)(A + (size_t)node * 128 + q * 32);
    #pragma unroll
    for (int kk = 0; kk < 4; kk++) {
        float4 raw = arow[kk];             // 8 halves
        __half2* hh = (__half2*)&raw;
        #pragma unroll
        for (int j = 0; j < 4; j++) {
            float2 f = __half22float2(hh[j]);
            int k = q * 32 + kk * 8 + j * 2;
            #pragma unroll
            for (int c = 0; c < CLS; c++)
                acc[c] += f.x * W2s[k * CLS + c] + f.y * W2s[(k + 1) * CLS + c];
        }
    }
    #pragma unroll
    for (int c = 0; c < CLS; c++) {
        acc[c] += __shfl_xor(acc[c], 1, 4);
        acc[c] += __shfl_xor(acc[c], 2, 4);
    }
    if (q == 0) {
        float s = 0.f, d = 0.f;
        float* row = hp2 + (size_t)node * CLS_PAD;
        #pragma unroll
        for (int c = 0; c < CLS; c++) {
            row[c] = acc[c];
            s += acc[c] * av[c];
            d += acc[c] * av[CLS + c];
        }
        asn[node] = s;
        adn[node] = d;
    }
}

__global__ __launch_bounds__(256) void gat_aggr2(const float* __restrict__ hp2,
                                                 const float* __restrict__ asn,
                                                 const float* __restrict__ adn,
                                                 const int* __restrict__ ptr,
                                                 const int* __restrict__ csr,
                                                 const float* __restrict__ b2,
                                                 float* __restrict__ out) {
    int gid = blockIdx.x * blockDim.x + threadIdx.x;
    int node = gid >> 4;
    int c = gid & 15;
    if (node >= N_NODES) return;
    int beg = ptr[node], end = ptr[node + 1];
    int cc = (c < CLS) ? c : 0;
    float adv = adn[node];
    float acc = 0.f, l = 0.f;
    int i = beg;
    for (; i + 7 < end; i += 8) {
        int s0 = csr[i],     s1 = csr[i + 1], s2 = csr[i + 2], s3 = csr[i + 3];
        int s4 = csr[i + 4], s5 = csr[i + 5], s6 = csr[i + 6], s7 = csr[i + 7];
        float al0 = asn[s0] + adv;
        float al1 = asn[s1] + adv;
        float al2 = asn[s2] + adv;
        float al3 = asn[s3] + adv;
        float al4 = asn[s4] + adv;
        float al5 = asn[s5] + adv;
        float al6 = asn[s6] + adv;
        float al7 = asn[s7] + adv;
        al0 = (al0 > 0.f) ? al0 : 0.2f * al0;
        al1 = (al1 > 0.f) ? al1 : 0.2f * al1;
        al2 = (al2 > 0.f) ? al2 : 0.2f * al2;
        al3 = (al3 > 0.f) ? al3 : 0.2f * al3;
        al4 = (al4 > 0.f) ? al4 : 0.2f * al4;
        al5 = (al5 > 0.f) ? al5 : 0.2f * al5;
        al6 = (al6 > 0.f) ? al6 : 0.2f * al6;
        al7 = (al7 > 0.f) ? al7 : 0.2f * al7;
        float w0 = __expf(al0), w1 = __expf(al1), w2 = __expf(al2), w3 = __expf(al3);
        float w4 = __expf(al4), w5 = __expf(al5), w6 = __expf(al6), w7 = __expf(al7);
        float v0 = hp2[(size_t)s0 * CLS_PAD + cc];
        float v1 = hp2[(size_t)s1 * CLS_PAD + cc];
        float v2 = hp2[(size_t)s2 * CLS_PAD + cc];
        float v3 = hp2[(size_t)s3 * CLS_PAD + cc];
        float v4 = hp2[(size_t)s4 * CLS_PAD + cc];
        float v5 = hp2[(size_t)s5 * CLS_PAD + cc];
        float v6 = hp2[(size_t)s6 * CLS_PAD + cc];
        float v7 = hp2[(size_t)s7 * CLS_PAD + cc];
        l   += w0 + w1 + w2 + w3;
        acc += w0 * v0 + w1 * v1 + w2 * v2 + w3 * v3;
        l   += w4 + w5 + w6 + w7;
        acc += w4 * v4 + w5 * v5 + w6 * v6 + w7 * v7;
    }
    for (; i + 3 < end; i += 4) {
        int s0 = csr[i], s1 = csr[i + 1], s2 = csr[i + 2], s3 = csr[i + 3];
        float al0 = asn[s0] + adv;
        float al1 = asn[s1] + adv;
        float al2 = asn[s2] + adv;
        float al3 = asn[s3] + adv;
        al0 = (al0 > 0.f) ? al0 : 0.2f * al0;
        al1 = (al1 > 0.f) ? al1 : 0.2f * al1;
        al2 = (al2 > 0.f) ? al2 : 0.2f * al2;
        al3 = (al3 > 0.f) ? al3 : 0.2f * al3;
        float w0 = __expf(al0), w1 = __expf(al1), w2 = __expf(al2), w3 = __expf(al3);
        float v0 = hp2[(size_t)s0 * CLS_PAD + cc];
        float v1 = hp2[(size_t)s1 * CLS_PAD + cc];
        float v2 = hp2[(size_t)s2 * CLS_PAD + cc];
        float v3 = hp2[(size_t)s3 * CLS_PAD + cc];
        l   += w0 + w1 + w2 + w3;
        acc += w0 * v0 + w1 * v1 + w2 * v2 + w3 * v3;
    }
    for (; i < end; i++) {
        int s0 = csr[i];
        float al = asn[s0] + adv;
        al = (al > 0.f) ? al : 0.2f * al;
        float w = __expf(al);
        l += w;
        acc += w * hp2[(size_t)s0 * CLS_PAD + cc];
    }
    if (c < CLS) out[(size_t)node * CLS + c] = acc / (l + 1e-16f) + b2[c];
}

// ---------------- launch ----------------

extern "C" void kernel_launch(void* const* d_in, const int* in_sizes, int n_in,
                              void* d_out, int out_size, void* d_ws, size_t ws_size,
                              hipStream_t stream) {
    const float* x   = (const float*)d_in[0];
    const int*   ei  = (const int*)  d_in[1];
    const float* W0  = (const float*)d_in[2];
    const float* as0 = (const float*)d_in[3];
    const float* ad0 = (const float*)d_in[4];
    const float* b0  = (const float*)d_in[5];
    const float* g0  = (const float*)d_in[6];
    const float* be0 = (const float*)d_in[7];
    const float* W1  = (const float*)d_in[8];
    const float* as1 = (const float*)d_in[9];
    const float* ad1 = (const float*)d_in[10];
    const float* b1  = (const float*)d_in[11];
    const float* g1  = (const float*)d_in[12];
    const float* be1 = (const float*)d_in[13];
    const float* W2  = (const float*)d_in[14];
    const float* as2 = (const float*)d_in[15];
    const float* ad2 = (const float*)d_in[16];
    const float* b2  = (const float*)d_in[17];

    char* ws = (char*)d_ws;
    size_t off = 0;
    auto alloc = [&](size_t bytes) -> void* {
        void* p = ws + off;
        off += (bytes + 255) & ~(size_t)255;
        return p;
    };
    int*    ptr    = (int*)   alloc((N_NODES + 1) * sizeof(int));
    int*    cursor = (int*)   alloc(N_NODES * sizeof(int));
    int*    bsums  = (int*)   alloc(64 * sizeof(int));
    int*    csr    = (int*)   alloc(E_TOT * sizeof(int));
    __half* hp     = (__half*)alloc((size_t)N_NODES * 128 * sizeof(__half));
    __half* hc     = (__half*)alloc((size_t)N_NODES * 128 * sizeof(__half));
    float*  a_s    = (float*) alloc(N_NODES * 4 * sizeof(float));
    float*  a_d    = (float*) alloc(N_NODES * 4 * sizeof(float));
    float*  hp2    = (float*) alloc((size_t)N_NODES * CLS_PAD * sizeof(float));
    float*  asn    = (float*) alloc(N_NODES * sizeof(float));
    float*  adn    = (float*) alloc(N_NODES * sizeof(float));
    __half* Wt0    = (__half*)alloc(128 * 128 * sizeof(__half));
    __half* Wt1    = (__half*)alloc(128 * 128 * sizeof(__half));

    // ---- CSR build ----
    hipMemsetAsync(cursor, 0, N_NODES * sizeof(int), stream);
    count_deg<<<(N_EDGES + 255) / 256, 256, 0, stream>>>(ei, cursor);
    int nScanBlocks = (N_NODES + SCAN_BLOCK * SCAN_ITEMS - 1) / (SCAN_BLOCK * SCAN_ITEMS);
    scan1<<<nScanBlocks, SCAN_BLOCK, 0, stream>>>(cursor, ptr, bsums, N_NODES);
    scan2<<<1, 64, 0, stream>>>(bsums, nScanBlocks);
    scan3<<<(N_NODES + 255) / 256, 256, 0, stream>>>(ptr, bsums, cursor, csr, N_NODES, E_TOT);
    scatter_edges<<<(N_EDGES + 255) / 256, 256, 0, stream>>>(ei, cursor, csr);

    // ---- weight pre-convert (independent of CSR) ----
    conv_w<<<64, 256, 0, stream>>>(W0, W1, Wt0, Wt1);

    int gemmBlocks = (N_NODES + 63) / 64;

    // ---- layer 0 ----
    gemm_att_mfma<false><<<gemmBlocks, 256, 0, stream>>>(x, Wt0, as0, ad0, hp, a_s, a_d, N_NODES);
    gat_aggr<<<N_NODES / 2, 128, 0, stream>>>((const __half2*)hp, a_s, a_d, ptr, csr,
                                              b0, g0, be0, (__half2*)hc);

    // ---- layer 1 ----
    gemm_att_mfma<true><<<gemmBlocks, 256, 0, stream>>>(hc, Wt1, as1, ad1, hp, a_s, a_d, N_NODES);
    gat_aggr<<<N_NODES / 2, 128, 0, stream>>>((const __half2*)hp, a_s, a_d, ptr, csr,
                                              b1, g1, be1, (__half2*)hc);

    // ---- layer 2 ----
    cls_fused<<<(N_NODES + 63) / 64, 256, 0, stream>>>(hc, W2, as2, ad2, hp2, asn, adn);
    gat_aggr2<<<(N_NODES * 16 + 255) / 256, 256, 0, stream>>>(hp2, asn, adn, ptr, csr, b2,
                                                              (float*)d_out);
}

// Round 9
// 288.925 us; speedup vs baseline: 1.1101x; 1.0125x over previous
//
#include <hip/hip_runtime.h>
#include <hip/hip_bf16.h>
#include <hip/hip_fp16.h>
#include <math.h>

#define N_NODES 50000
#define N_EDGES 600000
#define E_TOT   (N_EDGES + N_NODES)   // 650000 edges incl self-loops
#define F       128
#define HEADS   4
#define DHEAD   32
#define CLS     10
#define CLS_PAD 16

// ---------------- CSR build (self-loops placed deterministically, no atomics for them) ----------------

__global__ void count_deg(const int* __restrict__ ei, int* __restrict__ deg) {
    int e = blockIdx.x * blockDim.x + threadIdx.x;
    if (e >= N_EDGES) return;
    atomicAdd(&deg[ei[N_EDGES + e]], 1);
}

#define SCAN_BLOCK 256
#define SCAN_ITEMS 4   // chunk = 1024

__global__ void scan1(const int* __restrict__ deg, int* __restrict__ ptr,
                      int* __restrict__ blockSums, int n) {
    __shared__ int sdata[SCAN_BLOCK];
    int t = threadIdx.x;
    int base = blockIdx.x * (SCAN_BLOCK * SCAN_ITEMS) + t * SCAN_ITEMS;
    int v[SCAN_ITEMS];
    int sum = 0;
    #pragma unroll
    for (int i = 0; i < SCAN_ITEMS; i++) {
        int idx = base + i;
        v[i] = (idx < n) ? (deg[idx] + 1) : 0;   // +1 = self-loop
        sum += v[i];
    }
    sdata[t] = sum;
    __syncthreads();
    for (int off = 1; off < SCAN_BLOCK; off <<= 1) {
        int x = 0;
        if (t >= off) x = sdata[t - off];
        __syncthreads();
        if (t >= off) sdata[t] += x;
        __syncthreads();
    }
    int excl = (t > 0) ? sdata[t - 1] : 0;
    if (t == SCAN_BLOCK - 1) blockSums[blockIdx.x] = sdata[t];   // chunk TOTAL
    int run = excl;
    #pragma unroll
    for (int i = 0; i < SCAN_ITEMS; i++) {
        int idx = base + i;
        if (idx < n) ptr[idx] = run;
        run += v[i];
    }
}

// scan2 merged into scan3: each scan3 block covers exactly one 1024-chunk
// (256 threads x 1 chunk), so it needs ONE prefix = sum of blockSums[0..chunk-1],
// computed by wave 0 via a 64-lane shuffle reduction (nb <= 64).

__global__ void scan3(int* __restrict__ ptr, const int* __restrict__ blockSums,
                      int* __restrict__ cursor, int* __restrict__ csr, int n, int total,
                      int nb) {
    __shared__ int sprefix;
    int t = threadIdx.x;
    int chunk = blockIdx.x >> 2;             // (blockIdx.x*256)/1024, constant per block
    if (t < 64) {
        int v = (t < chunk) ? blockSums[t] : 0;   // chunk <= 48 < nb
        #pragma unroll
        for (int off = 1; off < 64; off <<= 1) v += __shfl_xor(v, off);
        if (t == 0) sprefix = v;
    }
    __syncthreads();
    int pre = sprefix;
    int i = blockIdx.x * blockDim.x + t;
    if (i < n) {
        int v = ptr[i] + pre;
        ptr[i] = v;
        cursor[i] = v + 1;   // real edges start after the self-loop slot
        csr[v] = i;          // self-loop first
    }
    if (i == 0) ptr[n] = total;
}

__global__ void scatter_edges(const int* __restrict__ ei, int* __restrict__ cursor,
                              int* __restrict__ csr_src) {
    int e = blockIdx.x * blockDim.x + threadIdx.x;
    if (e >= N_EDGES) return;
    int s = ei[e], d = ei[N_EDGES + e];
    int pos = atomicAdd(&cursor[d], 1);
    csr_src[pos] = s;
}

// ---------------- W pre-convert: fp32 [k][c] -> fp16 transposed [c][k], XOR-swizzled ----------------

__global__ __launch_bounds__(256) void conv_w(const float* __restrict__ W0,
                                              const float* __restrict__ W1,
                                              __half* __restrict__ Wt0,
                                              __half* __restrict__ Wt1) {
    int idx = blockIdx.x * 256 + threadIdx.x;
    if (idx >= 128 * 128) return;
    int k = idx >> 7, c = idx & 127;
    int e = k ^ ((c & 7) << 3);
    Wt0[c * 128 + e] = __float2half(W0[idx]);
    Wt1[c * 128 + e] = __float2half(W1[idx]);
}

// ---------------- MFMA GEMM + fused attention coefficients ----------------
// SWAPPED operand order: mfma(bf, af) -> lane holds ROW lr, 4 consecutive COLS
// (c2*16 + lg*4 + r). hp store = 8x 8B packed stores; att reduce = 2 shfl rounds.

using half8_t  = __attribute__((ext_vector_type(8))) _Float16;
using floatx4  = __attribute__((ext_vector_type(4))) float;

template<bool HALF_IN>
__global__ __launch_bounds__(256) void gemm_att_mfma(const void* __restrict__ Ain,
                                                     const __half* __restrict__ Wt,
                                                     const float* __restrict__ att_s,
                                                     const float* __restrict__ att_d,
                                                     __half* __restrict__ C,
                                                     float* __restrict__ a_s,
                                                     float* __restrict__ a_d, int nrows) {
    __shared__ _Float16 As[64 * 128];    // 16 KB, swizzled rows
    __shared__ _Float16 Ws[128 * 128];   // 32 KB, pre-swizzled [col][k]
    int t = threadIdx.x;
    int row0 = blockIdx.x * 64;

    // stage Ws: linear 32 KB copy (Wt already transposed+swizzled)
    #pragma unroll
    for (int idx = t; idx < 128 * 128 / 8; idx += 256)
        ((float4*)Ws)[idx] = ((const float4*)Wt)[idx];

    // stage As: 64 rows x 16 groups of 8 elems, swizzled write
    if constexpr (HALF_IN) {
        const __half* A = (const __half*)Ain;
        #pragma unroll
        for (int idx = t; idx < 64 * 16; idx += 256) {
            int r = idx >> 4, g = idx & 15;
            float4 v = make_float4(0.f, 0.f, 0.f, 0.f);
            if (row0 + r < nrows)
                v = *(const float4*)(A + (size_t)(row0 + r) * 128 + g * 8);
            int gs = g ^ (r & 7);
            *(float4*)&As[r * 128 + (gs << 3)] = v;
        }
    } else {
        const float* A = (const float*)Ain;
        #pragma unroll
        for (int idx = t; idx < 64 * 16; idx += 256) {
            int r = idx >> 4, g = idx & 15;
            float4 v0 = make_float4(0.f, 0.f, 0.f, 0.f), v1 = v0;
            if (row0 + r < nrows) {
                const float4* p = (const float4*)(A + (size_t)(row0 + r) * 128 + g * 8);
                v0 = p[0]; v1 = p[1];
            }
            int gs = g ^ (r & 7);
            union { _Float16 h[8]; float4 f; } u;
            u.h[0] = (_Float16)v0.x; u.h[1] = (_Float16)v0.y;
            u.h[2] = (_Float16)v0.z; u.h[3] = (_Float16)v0.w;
            u.h[4] = (_Float16)v1.x; u.h[5] = (_Float16)v1.y;
            u.h[6] = (_Float16)v1.z; u.h[7] = (_Float16)v1.w;
            *(float4*)&As[r * 128 + (gs << 3)] = u.f;
        }
    }
    __syncthreads();

    int wave = t >> 6, l = t & 63;
    int lr = l & 15, lg = l >> 4;        // lr: row lane, lg: k-group / col-quad
    int arow = wave * 16 + lr;

    floatx4 acc[8];
    #pragma unroll
    for (int c2 = 0; c2 < 8; c2++) acc[c2] = (floatx4){0.f, 0.f, 0.f, 0.f};

    #pragma unroll
    for (int ks = 0; ks < 4; ks++) {
        int gk = ks * 4 + lg;            // k-octet index
        half8_t af = *(const half8_t*)&As[arow * 128 + ((gk ^ (arow & 7)) << 3)];
        #pragma unroll
        for (int c2 = 0; c2 < 8; c2++) {
            int col = c2 * 16 + lr;
            half8_t bf = *(const half8_t*)&Ws[col * 128 + ((gk ^ (col & 7)) << 3)];
            // swapped: D^T -> lane holds row=arow, cols c2*16 + lg*4 + {0..3}
            acc[c2] = __builtin_amdgcn_mfma_f32_16x16x32_f16(bf, af, acc[c2], 0, 0, 0);
        }
    }

    int row = row0 + arow;
    bool rowOk = row < nrows;

    // store hp row: 8B packed per c2
    #pragma unroll
    for (int c2 = 0; c2 < 8; c2++) {
        __half2 p0 = __floats2half2_rn(acc[c2][0], acc[c2][1]);
        __half2 p1 = __floats2half2_rn(acc[c2][2], acc[c2][3]);
        uint2 u;
        u.x = *(unsigned*)&p0;
        u.y = *(unsigned*)&p1;
        if (rowOk) ((uint2*)C)[(size_t)row * 32 + c2 * 4 + lg] = u;
    }

    // attention dots: per lane partial over its 32 cols, reduce over lg lanes
    float ps[4] = {0.f, 0.f, 0.f, 0.f}, pd[4] = {0.f, 0.f, 0.f, 0.f};
    #pragma unroll
    for (int c2 = 0; c2 < 8; c2++) {
        #pragma unroll
        for (int r = 0; r < 4; r++) {
            int col = c2 * 16 + lg * 4 + r;
            float v = acc[c2][r];
            ps[c2 >> 1] += v * att_s[col];
            pd[c2 >> 1] += v * att_d[col];
        }
    }
    #pragma unroll
    for (int hh = 0; hh < 4; hh++) {
        ps[hh] += __shfl_xor(ps[hh], 16); ps[hh] += __shfl_xor(ps[hh], 32);
        pd[hh] += __shfl_xor(pd[hh], 16); pd[hh] += __shfl_xor(pd[hh], 32);
    }
    if (lg == 0 && rowOk) {
        *(float4*)(a_s + (size_t)row * 4) = make_float4(ps[0], ps[1], ps[2], ps[3]);
        *(float4*)(a_d + (size_t)row * 4) = make_float4(pd[0], pd[1], pd[2], pd[3]);
    }
}

// ---------------- single-pass aggregate (R5-proven: unroll-8 -> unroll-4 -> tail) ----------
// 2 nodes/block, 64 threads/node, half2 per lane (2 cols). exp fused inline.
// node wave-uniform via readfirstlane -> ptr/csr loads stay scalar (s_load).

__global__ __launch_bounds__(128) void gat_aggr(const __half2* __restrict__ hp,
                                                const float* __restrict__ a_s,
                                                const float* __restrict__ a_d,
                                                const int* __restrict__ ptr,
                                                const int* __restrict__ csr,
                                                const float* __restrict__ bias,
                                                const float* __restrict__ gamma,
                                                const float* __restrict__ beta,
                                                __half2* __restrict__ out) {
    int t = threadIdx.x;
    int node = __builtin_amdgcn_readfirstlane(blockIdx.x * 2 + (t >> 6));
    int local = t & 63;
    int h = local >> 4;
    int beg = ptr[node], end = ptr[node + 1];
    float adh = a_d[(size_t)node * 4 + h];
    float ax = 0.f, ay = 0.f, l = 0.f;
    int i = beg;
    for (; i + 7 < end; i += 8) {
        int s0 = csr[i],     s1 = csr[i + 1], s2 = csr[i + 2], s3 = csr[i + 3];
        int s4 = csr[i + 4], s5 = csr[i + 5], s6 = csr[i + 6], s7 = csr[i + 7];
        float al0 = a_s[(size_t)s0 * 4 + h] + adh;
        float al1 = a_s[(size_t)s1 * 4 + h] + adh;
        float al2 = a_s[(size_t)s2 * 4 + h] + adh;
        float al3 = a_s[(size_t)s3 * 4 + h] + adh;
        float al4 = a_s[(size_t)s4 * 4 + h] + adh;
        float al5 = a_s[(size_t)s5 * 4 + h] + adh;
        float al6 = a_s[(size_t)s6 * 4 + h] + adh;
        float al7 = a_s[(size_t)s7 * 4 + h] + adh;
        al0 = (al0 > 0.f) ? al0 : 0.2f * al0;
        al1 = (al1 > 0.f) ? al1 : 0.2f * al1;
        al2 = (al2 > 0.f) ? al2 : 0.2f * al2;
        al3 = (al3 > 0.f) ? al3 : 0.2f * al3;
        al4 = (al4 > 0.f) ? al4 : 0.2f * al4;
        al5 = (al5 > 0.f) ? al5 : 0.2f * al5;
        al6 = (al6 > 0.f) ? al6 : 0.2f * al6;
        al7 = (al7 > 0.f) ? al7 : 0.2f * al7;
        float w0 = __expf(al0), w1 = __expf(al1), w2 = __expf(al2), w3 = __expf(al3);
        float w4 = __expf(al4), w5 = __expf(al5), w6 = __expf(al6), w7 = __expf(al7);
        float2 v0 = __half22float2(hp[(size_t)s0 * 64 + local]);
        float2 v1 = __half22float2(hp[(size_t)s1 * 64 + local]);
        float2 v2 = __half22float2(hp[(size_t)s2 * 64 + local]);
        float2 v3 = __half22float2(hp[(size_t)s3 * 64 + local]);
        float2 v4 = __half22float2(hp[(size_t)s4 * 64 + local]);
        float2 v5 = __half22float2(hp[(size_t)s5 * 64 + local]);
        float2 v6 = __half22float2(hp[(size_t)s6 * 64 + local]);
        float2 v7 = __half22float2(hp[(size_t)s7 * 64 + local]);
        l  += w0 + w1 + w2 + w3;
        ax += w0 * v0.x + w1 * v1.x + w2 * v2.x + w3 * v3.x;
        ay += w0 * v0.y + w1 * v1.y + w2 * v2.y + w3 * v3.y;
        l  += w4 + w5 + w6 + w7;
        ax += w4 * v4.x + w5 * v5.x + w6 * v6.x + w7 * v7.x;
        ay += w4 * v4.y + w5 * v5.y + w6 * v6.y + w7 * v7.y;
    }
    for (; i + 3 < end; i += 4) {
        int s0 = csr[i], s1 = csr[i + 1], s2 = csr[i + 2], s3 = csr[i + 3];
        float al0 = a_s[(size_t)s0 * 4 + h] + adh;
        float al1 = a_s[(size_t)s1 * 4 + h] + adh;
        float al2 = a_s[(size_t)s2 * 4 + h] + adh;
        float al3 = a_s[(size_t)s3 * 4 + h] + adh;
        al0 = (al0 > 0.f) ? al0 : 0.2f * al0;
        al1 = (al1 > 0.f) ? al1 : 0.2f * al1;
        al2 = (al2 > 0.f) ? al2 : 0.2f * al2;
        al3 = (al3 > 0.f) ? al3 : 0.2f * al3;
        float w0 = __expf(al0), w1 = __expf(al1), w2 = __expf(al2), w3 = __expf(al3);
        float2 v0 = __half22float2(hp[(size_t)s0 * 64 + local]);
        float2 v1 = __half22float2(hp[(size_t)s1 * 64 + local]);
        float2 v2 = __half22float2(hp[(size_t)s2 * 64 + local]);
        float2 v3 = __half22float2(hp[(size_t)s3 * 64 + local]);
        l  += w0 + w1 + w2 + w3;
        ax += w0 * v0.x + w1 * v1.x + w2 * v2.x + w3 * v3.x;
        ay += w0 * v0.y + w1 * v1.y + w2 * v2.y + w3 * v3.y;
    }
    for (; i < end; i++) {
        int s0 = csr[i];
        float al = a_s[(size_t)s0 * 4 + h] + adh;
        al = (al > 0.f) ? al : 0.2f * al;
        float w = __expf(al);
        float2 v = __half22float2(hp[(size_t)s0 * 64 + local]);
        l  += w;
        ax += w * v.x;
        ay += w * v.y;
    }
    float inv = 1.f / (l + 1e-16f);
    int c = local * 2;
    const float rs = rsqrtf(1.f + 1e-5f);
    float2 bs = *(const float2*)(bias + c);
    float2 gm = *(const float2*)(gamma + c);
    float2 bt = *(const float2*)(beta + c);
    float vx = ax * inv + bs.x;
    float vy = ay * inv + bs.y;
    vx = vx * (gm.x * rs) + bt.x;
    vy = vy * (gm.y * rs) + bt.y;
    vx = (vx > 0.f) ? vx : expm1f(vx);
    vy = (vy > 0.f) ? vy : expm1f(vy);
    out[(size_t)node * 64 + local] = __floats2half2_rn(vx, vy);
}

// ---------------- layer 2: fused [N,128]@[128,10] GEMM + coefficients (A in fp16) ----------------
// hp2 now stored fp16 (32B rows) -> halves gat_aggr2's random-gather line fetches.

__global__ __launch_bounds__(256) void cls_fused(const __half* __restrict__ A,
                                                 const float* __restrict__ W2,
                                                 const float* __restrict__ as2,
                                                 const float* __restrict__ ad2,
                                                 __half* __restrict__ hp2,
                                                 float* __restrict__ asn,
                                                 float* __restrict__ adn) {
    __shared__ float W2s[128 * CLS];
    __shared__ float av[2 * CLS];
    int t = threadIdx.x;
    for (int idx = t; idx < 128 * CLS; idx += 256) W2s[idx] = W2[idx];
    if (t < CLS) av[t] = as2[t];
    else if (t < 2 * CLS) av[t] = ad2[t - CLS];
    __syncthreads();

    int node = blockIdx.x * 64 + (t >> 2);
    int q = t & 3;
    if (node >= N_NODES) return;
    float acc[CLS];
    #pragma unroll
    for (int c = 0; c < CLS; c++) acc[c] = 0.f;
    const float4* arow = (const float4*)(A + (size_t)node * 128 + q * 32);
    #pragma unroll
    for (int kk = 0; kk < 4; kk++) {
        float4 raw = arow[kk];             // 8 halves
        __half2* hh = (__half2*)&raw;
        #pragma unroll
        for (int j = 0; j < 4; j++) {
            float2 f = __half22float2(hh[j]);
            int k = q * 32 + kk * 8 + j * 2;
            #pragma unroll
            for (int c = 0; c < CLS; c++)
                acc[c] += f.x * W2s[k * CLS + c] + f.y * W2s[(k + 1) * CLS + c];
        }
    }
    #pragma unroll
    for (int c = 0; c < CLS; c++) {
        acc[c] += __shfl_xor(acc[c], 1, 4);
        acc[c] += __shfl_xor(acc[c], 2, 4);
    }
    if (q == 0) {
        float s = 0.f, d = 0.f;
        __half* row = hp2 + (size_t)node * CLS_PAD;
        #pragma unroll
        for (int c = 0; c < CLS; c++) {
            row[c] = __float2half(acc[c]);
            s += acc[c] * av[c];
            d += acc[c] * av[CLS + c];
        }
        asn[node] = s;
        adn[node] = d;
    }
}

__global__ __launch_bounds__(256) void gat_aggr2(const __half* __restrict__ hp2,
                                                 const float* __restrict__ asn,
                                                 const float* __restrict__ adn,
                                                 const int* __restrict__ ptr,
                                                 const int* __restrict__ csr,
                                                 const float* __restrict__ b2,
                                                 float* __restrict__ out) {
    int gid = blockIdx.x * blockDim.x + threadIdx.x;
    int node = gid >> 4;
    int c = gid & 15;
    if (node >= N_NODES) return;
    int beg = ptr[node], end = ptr[node + 1];
    int cc = (c < CLS) ? c : 0;
    float adv = adn[node];
    float acc = 0.f, l = 0.f;
    int i = beg;
    for (; i + 7 < end; i += 8) {
        int s0 = csr[i],     s1 = csr[i + 1], s2 = csr[i + 2], s3 = csr[i + 3];
        int s4 = csr[i + 4], s5 = csr[i + 5], s6 = csr[i + 6], s7 = csr[i + 7];
        float al0 = asn[s0] + adv;
        float al1 = asn[s1] + adv;
        float al2 = asn[s2] + adv;
        float al3 = asn[s3] + adv;
        float al4 = asn[s4] + adv;
        float al5 = asn[s5] + adv;
        float al6 = asn[s6] + adv;
        float al7 = asn[s7] + adv;
        al0 = (al0 > 0.f) ? al0 : 0.2f * al0;
        al1 = (al1 > 0.f) ? al1 : 0.2f * al1;
        al2 = (al2 > 0.f) ? al2 : 0.2f * al2;
        al3 = (al3 > 0.f) ? al3 : 0.2f * al3;
        al4 = (al4 > 0.f) ? al4 : 0.2f * al4;
        al5 = (al5 > 0.f) ? al5 : 0.2f * al5;
        al6 = (al6 > 0.f) ? al6 : 0.2f * al6;
        al7 = (al7 > 0.f) ? al7 : 0.2f * al7;
        float w0 = __expf(al0), w1 = __expf(al1), w2 = __expf(al2), w3 = __expf(al3);
        float w4 = __expf(al4), w5 = __expf(al5), w6 = __expf(al6), w7 = __expf(al7);
        float v0 = __half2float(hp2[(size_t)s0 * CLS_PAD + cc]);
        float v1 = __half2float(hp2[(size_t)s1 * CLS_PAD + cc]);
        float v2 = __half2float(hp2[(size_t)s2 * CLS_PAD + cc]);
        float v3 = __half2float(hp2[(size_t)s3 * CLS_PAD + cc]);
        float v4 = __half2float(hp2[(size_t)s4 * CLS_PAD + cc]);
        float v5 = __half2float(hp2[(size_t)s5 * CLS_PAD + cc]);
        float v6 = __half2float(hp2[(size_t)s6 * CLS_PAD + cc]);
        float v7 = __half2float(hp2[(size_t)s7 * CLS_PAD + cc]);
        l   += w0 + w1 + w2 + w3;
        acc += w0 * v0 + w1 * v1 + w2 * v2 + w3 * v3;
        l   += w4 + w5 + w6 + w7;
        acc += w4 * v4 + w5 * v5 + w6 * v6 + w7 * v7;
    }
    for (; i + 3 < end; i += 4) {
        int s0 = csr[i], s1 = csr[i + 1], s2 = csr[i + 2], s3 = csr[i + 3];
        float al0 = asn[s0] + adv;
        float al1 = asn[s1] + adv;
        float al2 = asn[s2] + adv;
        float al3 = asn[s3] + adv;
        al0 = (al0 > 0.f) ? al0 : 0.2f * al0;
        al1 = (al1 > 0.f) ? al1 : 0.2f * al1;
        al2 = (al2 > 0.f) ? al2 : 0.2f * al2;
        al3 = (al3 > 0.f) ? al3 : 0.2f * al3;
        float w0 = __expf(al0), w1 = __expf(al1), w2 = __expf(al2), w3 = __expf(al3);
        float v0 = __half2float(hp2[(size_t)s0 * CLS_PAD + cc]);
        float v1 = __half2float(hp2[(size_t)s1 * CLS_PAD + cc]);
        float v2 = __half2float(hp2[(size_t)s2 * CLS_PAD + cc]);
        float v3 = __half2float(hp2[(size_t)s3 * CLS_PAD + cc]);
        l   += w0 + w1 + w2 + w3;
        acc += w0 * v0 + w1 * v1 + w2 * v2 + w3 * v3;
    }
    for (; i < end; i++) {
        int s0 = csr[i];
        float al = asn[s0] + adv;
        al = (al > 0.f) ? al : 0.2f * al;
        float w = __expf(al);
        l += w;
        acc += w * __half2float(hp2[(size_t)s0 * CLS_PAD + cc]);
    }
    if (c < CLS) out[(size_t)node * CLS + c] = acc / (l + 1e-16f) + b2[c];
}

// ---------------- launch ----------------

extern "C" void kernel_launch(void* const* d_in, const int* in_sizes, int n_in,
                              void* d_out, int out_size, void* d_ws, size_t ws_size,
                              hipStream_t stream) {
    const float* x   = (const float*)d_in[0];
    const int*   ei  = (const int*)  d_in[1];
    const float* W0  = (const float*)d_in[2];
    const float* as0 = (const float*)d_in[3];
    const float* ad0 = (const float*)d_in[4];
    const float* b0  = (const float*)d_in[5];
    const float* g0  = (const float*)d_in[6];
    const float* be0 = (const float*)d_in[7];
    const float* W1  = (const float*)d_in[8];
    const float* as1 = (const float*)d_in[9];
    const float* ad1 = (const float*)d_in[10];
    const float* b1  = (const float*)d_in[11];
    const float* g1  = (const float*)d_in[12];
    const float* be1 = (const float*)d_in[13];
    const float* W2  = (const float*)d_in[14];
    const float* as2 = (const float*)d_in[15];
    const float* ad2 = (const float*)d_in[16];
    const float* b2  = (const float*)d_in[17];

    char* ws = (char*)d_ws;
    size_t off = 0;
    auto alloc = [&](size_t bytes) -> void* {
        void* p = ws + off;
        off += (bytes + 255) & ~(size_t)255;
        return p;
    };
    int*    ptr    = (int*)   alloc((N_NODES + 1) * sizeof(int));
    int*    cursor = (int*)   alloc(N_NODES * sizeof(int));
    int*    bsums  = (int*)   alloc(64 * sizeof(int));
    int*    csr    = (int*)   alloc(E_TOT * sizeof(int));
    __half* hp     = (__half*)alloc((size_t)N_NODES * 128 * sizeof(__half));
    __half* hc     = (__half*)alloc((size_t)N_NODES * 128 * sizeof(__half));
    float*  a_s    = (float*) alloc(N_NODES * 4 * sizeof(float));
    float*  a_d    = (float*) alloc(N_NODES * 4 * sizeof(float));
    __half* hp2    = (__half*)alloc((size_t)N_NODES * CLS_PAD * sizeof(__half));
    float*  asn    = (float*) alloc(N_NODES * sizeof(float));
    float*  adn    = (float*) alloc(N_NODES * sizeof(float));
    __half* Wt0    = (__half*)alloc(128 * 128 * sizeof(__half));
    __half* Wt1    = (__half*)alloc(128 * 128 * sizeof(__half));

    // ---- CSR build ----
    hipMemsetAsync(cursor, 0, N_NODES * sizeof(int), stream);
    count_deg<<<(N_EDGES + 255) / 256, 256, 0, stream>>>(ei, cursor);
    int nScanBlocks = (N_NODES + SCAN_BLOCK * SCAN_ITEMS - 1) / (SCAN_BLOCK * SCAN_ITEMS);
    scan1<<<nScanBlocks, SCAN_BLOCK, 0, stream>>>(cursor, ptr, bsums, N_NODES);
    scan3<<<(N_NODES + 255) / 256, 256, 0, stream>>>(ptr, bsums, cursor, csr, N_NODES, E_TOT,
                                                     nScanBlocks);
    scatter_edges<<<(N_EDGES + 255) / 256, 256, 0, stream>>>(ei, cursor, csr);

    // ---- weight pre-convert (independent of CSR) ----
    conv_w<<<64, 256, 0, stream>>>(W0, W1, Wt0, Wt1);

    int gemmBlocks = (N_NODES + 63) / 64;

    // ---- layer 0 ----
    gemm_att_mfma<false><<<gemmBlocks, 256, 0, stream>>>(x, Wt0, as0, ad0, hp, a_s, a_d, N_NODES);
    gat_aggr<<<N_NODES / 2, 128, 0, stream>>>((const __half2*)hp, a_s, a_d, ptr, csr,
                                              b0, g0, be0, (__half2*)hc);

    // ---- layer 1 ----
    gemm_att_mfma<true><<<gemmBlocks, 256, 0, stream>>>(hc, Wt1, as1, ad1, hp, a_s, a_d, N_NODES);
    gat_aggr<<<N_NODES / 2, 128, 0, stream>>>((const __half2*)hp, a_s, a_d, ptr, csr,
                                              b1, g1, be1, (__half2*)hc);

    // ---- layer 2 ----
    cls_fused<<<(N_NODES + 63) / 64, 256, 0, stream>>>(hc, W2, as2, ad2, hp2, asn, adn);
    gat_aggr2<<<(N_NODES * 16 + 255) / 256, 256, 0, stream>>>(hp2, asn, adn, ptr, csr, b2,
                                                              (float*)d_out);
}